// Round 10
// baseline (262.640 us; speedup 1.0000x reference)
//
#include <hip/hip_runtime.h>
#include <math.h>

#define T_DIM 2048
#define D_DIM 2048
#define NHEAD 16
#define DHEAD 128

typedef short v8s __attribute__((ext_vector_type(8)));   // 8 bf16 bit patterns
typedef float v4f __attribute__((ext_vector_type(4)));
typedef unsigned short ush;

#define MFMA16(a, b, c) __builtin_amdgcn_mfma_f32_16x16x32_bf16((a), (b), (c), 0, 0, 0)

__device__ __forceinline__ ush f2bf(float f) {
    unsigned u = __float_as_uint(f);
    u += 0x7FFF + ((u >> 16) & 1);          // RNE
    return (ush)(u >> 16);
}
__device__ __forceinline__ float bf2f(ush h) {
    return __uint_as_float((unsigned)h << 16);
}
__device__ __forceinline__ unsigned pack2(ush a, ush b) {
    return (unsigned)a | ((unsigned)b << 16);
}

__device__ __forceinline__ void gload_lds16(const ush* g, ush* l) {
    __builtin_amdgcn_global_load_lds(
        (const __attribute__((address_space(1))) void*)g,
        (__attribute__((address_space(3))) void*)l, 16, 0, 0);
}

// 2-D region XCD swizzle for a 16(m) x 32(n) grid of 512 blocks.
__device__ __forceinline__ void region_swizzle(int bid, int& m0, int& n0) {
    const int xcd = bid & 7;
    const int lg  = bid >> 3;                       // 0..63 within region
    const int mp  = ((xcd >> 2) << 3) + (lg >> 3);  // 0..15
    const int np  = ((xcd & 3) << 3) + (lg & 7);    // 0..31
    m0 = mp * 128;
    n0 = np * 64;
}

// ---------------------------------------------------------------------------
// split fp32 -> bf16 hi/lo. Single-matrix version (fallback path).
// ---------------------------------------------------------------------------
__global__ __launch_bounds__(256) void split_x(
    const float* __restrict__ X, ush* __restrict__ Xh, ush* __restrict__ Xl)
{
    const int i = (blockIdx.x * 256 + threadIdx.x) * 8;
    const float4 a = *(const float4*)&X[i];
    const float4 b = *(const float4*)&X[i + 4];
    const float f[8] = {a.x, a.y, a.z, a.w, b.x, b.y, b.z, b.w};
    ush h[8], l[8];
#pragma unroll
    for (int e = 0; e < 8; ++e) {
        h[e] = f2bf(f[e]);
        l[e] = f2bf(f[e] - bf2f(h[e]));
    }
    uint4 hv, lv;
    hv.x = pack2(h[0], h[1]); hv.y = pack2(h[2], h[3]);
    hv.z = pack2(h[4], h[5]); hv.w = pack2(h[6], h[7]);
    lv.x = pack2(l[0], l[1]); lv.y = pack2(l[2], l[3]);
    lv.z = pack2(l[4], l[5]); lv.w = pack2(l[6], l[7]);
    *(uint4*)&Xh[i] = hv;
    *(uint4*)&Xl[i] = lv;
}

// Fused 5-matrix split (x, Wq, Wk, Wv, Wo) — one launch.
struct Split5Args { const float* s[5]; ush* h[5]; ush* l[5]; };

__global__ __launch_bounds__(256) void split5(Split5Args a)
{
    const int m = blockIdx.y;
    const float* X = a.s[m];
    ush* Xh = a.h[m];
    ush* Xl = a.l[m];
    const int i = (blockIdx.x * 256 + threadIdx.x) * 8;
    const float4 p = *(const float4*)&X[i];
    const float4 q = *(const float4*)&X[i + 4];
    const float f[8] = {p.x, p.y, p.z, p.w, q.x, q.y, q.z, q.w};
    ush h[8], l[8];
#pragma unroll
    for (int e = 0; e < 8; ++e) {
        h[e] = f2bf(f[e]);
        l[e] = f2bf(f[e] - bf2f(h[e]));
    }
    uint4 hv, lv;
    hv.x = pack2(h[0], h[1]); hv.y = pack2(h[2], h[3]);
    hv.z = pack2(h[4], h[5]); hv.w = pack2(h[6], h[7]);
    lv.x = pack2(l[0], l[1]); lv.y = pack2(l[2], l[3]);
    lv.z = pack2(l[4], l[5]); lv.w = pack2(l[6], l[7]);
    *(uint4*)&Xh[i] = hv;
    *(uint4*)&Xl[i] = lv;
}

// ---------------------------------------------------------------------------
// GEMM C = A @ B^T + bias, bf16x3. Round-10: A-single + B-DOUBLE-buffer with
// counted vmcnt. Per step: raw barrier; issue A(t) [4 loads]; issue B(t+1)
// into alt buffer [2 loads]; vmcnt(2) (waits A(t)+B(t), B(t+1) stays in
// flight); raw barrier; compute. Only A's single L2 latency is exposed
// (~250cy vs round-9's ~1900cy full drain). LDS 64 KB -> 2 blocks/CU kept.
// ---------------------------------------------------------------------------
template <int MODE>
__global__ __launch_bounds__(512, 4) void gemm_x3(
    const ush* __restrict__ Ahg, const ush* __restrict__ Alg,
    const ush* __restrict__ Bhg, const ush* __restrict__ Blg,
    const float* __restrict__ bias, float scale,
    ush* __restrict__ Ob, float* __restrict__ Of)
{
    extern __shared__ ush xsmem[];   // Ah 8192 | Al 8192 | Bb0 h+l 8192 | Bb1 h+l 8192

    const int tid = threadIdx.x;
    const int l   = tid & 63;
    const int wid = tid >> 6;
    const int wm  = wid >> 1;
    const int wn  = wid & 1;
    const int cl  = l & 15;
    const int rg  = l >> 4;

    int m0, n0;
    region_swizzle(blockIdx.x, m0, n0);

    const int arow = tid >> 3;
    const int achk = tid & 7;
    const int axor = (achk ^ (arow & 7)) * 8;

    ush* Ah = xsmem;
    ush* Al = xsmem + 8192;

    auto stageA = [&](int k0) {      // 4 loads
        gload_lds16(&Ahg[(size_t)(m0 + arow) * D_DIM + k0 + axor],      &Ah[tid * 8]);
        gload_lds16(&Ahg[(size_t)(m0 + arow + 64) * D_DIM + k0 + axor], &Ah[(tid + 512) * 8]);
        gload_lds16(&Alg[(size_t)(m0 + arow) * D_DIM + k0 + axor],      &Al[tid * 8]);
        gload_lds16(&Alg[(size_t)(m0 + arow + 64) * D_DIM + k0 + axor], &Al[(tid + 512) * 8]);
    };
    auto stageB = [&](int which, int k0) {   // 2 loads
        ush* Bh = xsmem + 16384 + which * 8192;
        ush* Bl = Bh + 4096;
        gload_lds16(&Bhg[(size_t)(n0 + arow) * D_DIM + k0 + axor], &Bh[tid * 8]);
        gload_lds16(&Blg[(size_t)(n0 + arow) * D_DIM + k0 + axor], &Bl[tid * 8]);
    };

    v4f acc[2][2];
#pragma unroll
    for (int i = 0; i < 2; ++i)
#pragma unroll
        for (int j = 0; j < 2; ++j) acc[i][j] = (v4f)0.f;

    constexpr int NT = D_DIM / 64;   // 32
    stageB(0, 0);

    for (int ks = 0; ks < NT; ++ks) {
        __builtin_amdgcn_s_barrier();        // As & old B-buffer readers done
        stageA(ks * 64);
        if (ks + 1 < NT) {
            stageB((ks + 1) & 1, (ks + 1) * 64);
            asm volatile("s_waitcnt vmcnt(2)" ::: "memory");  // A(ks)+B(ks) landed
        } else {
            asm volatile("s_waitcnt vmcnt(0)" ::: "memory");
        }
        __builtin_amdgcn_s_barrier();        // staged data visible to all waves
        __builtin_amdgcn_sched_barrier(0);

        const ush* Bh = xsmem + 16384 + (ks & 1) * 8192;
        const ush* Bl = Bh + 4096;
#pragma unroll
        for (int kf = 0; kf < 2; ++kf) {
            const int c = kf * 4 + rg;
            v8s a_h[2], a_l[2], b_h[2], b_l[2];
#pragma unroll
            for (int mf = 0; mf < 2; ++mf) {
                const int r = wm * 32 + mf * 16 + cl;
                const int off = r * 64 + ((c ^ (r & 7)) * 8);
                a_h[mf] = *(const v8s*)&Ah[off];
                a_l[mf] = *(const v8s*)&Al[off];
            }
#pragma unroll
            for (int nf = 0; nf < 2; ++nf) {
                const int r = wn * 32 + nf * 16 + cl;
                const int off = r * 64 + ((c ^ (r & 7)) * 8);
                b_h[nf] = *(const v8s*)&Bh[off];
                b_l[nf] = *(const v8s*)&Bl[off];
            }
#pragma unroll
            for (int mf = 0; mf < 2; ++mf)
#pragma unroll
                for (int nf = 0; nf < 2; ++nf) {
                    acc[mf][nf] = MFMA16(a_h[mf], b_h[nf], acc[mf][nf]);
                    acc[mf][nf] = MFMA16(a_h[mf], b_l[nf], acc[mf][nf]);
                    acc[mf][nf] = MFMA16(a_l[mf], b_h[nf], acc[mf][nf]);
                }
        }
        asm volatile("" ::: "memory");
    }

#pragma unroll
    for (int mf = 0; mf < 2; ++mf)
#pragma unroll
        for (int nf = 0; nf < 2; ++nf) {
            const int n  = n0 + wn * 32 + nf * 16 + cl;
            const int mb = m0 + wm * 32 + mf * 16 + rg * 4;
            const float bv = bias[n];
            if (MODE == 0) {
#pragma unroll
                for (int j = 0; j < 4; ++j)
                    Ob[(size_t)(mb + j) * D_DIM + n] =
                        f2bf((acc[mf][nf][j] + bv) * scale);
            } else if (MODE == 1) {
                ushort4 pk;
                pk.x = f2bf(acc[mf][nf][0] + bv);
                pk.y = f2bf(acc[mf][nf][1] + bv);
                pk.z = f2bf(acc[mf][nf][2] + bv);
                pk.w = f2bf(acc[mf][nf][3] + bv);
                *(ushort4*)&Ob[(size_t)n * D_DIM + mb] = pk;   // Vt[n][m..m+3]
            } else {
#pragma unroll
                for (int j = 0; j < 4; ++j)
                    Of[(size_t)(mb + j) * D_DIM + n] = acc[mf][nf][j] + bv;
            }
        }
}

// ---------------------------------------------------------------------------
// FUSED QKV GEMM, bf16x3, hi|lo interleaved rows (conflict-free, round 7),
// region swizzle (round 9). Round-10: A-single + B-double-buffer counted
// vmcnt — vmcnt(3) keeps next tile's 3 B loads in flight across barriers.
// LDS: As 16 KB + 2 x 24 KB = 64 KB -> 2 blocks/CU kept.
// ---------------------------------------------------------------------------
__global__ __launch_bounds__(512, 4) void gemm_qkv(
    const ush* __restrict__ xh, const ush* __restrict__ xl,
    const ush* __restrict__ Wqh, const ush* __restrict__ Wql,
    const ush* __restrict__ Wkh, const ush* __restrict__ Wkl,
    const ush* __restrict__ Wvh, const ush* __restrict__ Wvl,
    const float* __restrict__ bq, const float* __restrict__ bk,
    const float* __restrict__ bv, float qscale,
    ush* __restrict__ Qo, ush* __restrict__ Ko, ush* __restrict__ Vto)
{
    extern __shared__ ush qsmem[];   // As 8192 | Bb0 12288 | Bb1 12288  (ush)

    const int tid = threadIdx.x;
    const int l   = tid & 63;
    const int wid = tid >> 6;
    const int wm  = wid >> 1;      // 0..3
    const int wn  = wid & 1;       // 0..1
    const int cl  = l & 15;
    const int rg  = l >> 4;

    int m0, n0;
    region_swizzle(blockIdx.x, m0, n0);

    const ush* Wh[3] = {Wqh, Wkh, Wvh};
    const ush* Wl[3] = {Wql, Wkl, Wvl};

    ush* As = qsmem;

    auto stageA = [&](int k0) {      // 2 loads: [128 rows][8 chunks] hi|lo interleave
#pragma unroll
        for (int i = 0; i < 2; ++i) {
            const int p   = i * 512 + tid;
            const int row = p >> 3;
            const int lc  = (p & 7) ^ (row & 7);
            const ush* src = (lc < 4 ? xh : xl) +
                             (size_t)(m0 + row) * D_DIM + k0 + (lc & 3) * 8;
            gload_lds16(src, &As[p * 8]);
        }
    };
    auto stageB = [&](int which, int k0) {   // 3 loads (one per weight)
        ush* buf = qsmem + 8192 + which * 12288;
        const int p   = tid;
        const int row = p >> 3;
        const int lc  = (p & 7) ^ (row & 7);
        const size_t off = (size_t)(n0 + row) * D_DIM + k0 + (lc & 3) * 8;
#pragma unroll
        for (int wg = 0; wg < 3; ++wg)
            gload_lds16((lc < 4 ? Wh[wg] : Wl[wg]) + off, &buf[wg * 4096 + p * 8]);
    };

    v4f acc[3][2][2];
#pragma unroll
    for (int wg = 0; wg < 3; ++wg)
#pragma unroll
        for (int i = 0; i < 2; ++i)
#pragma unroll
            for (int j = 0; j < 2; ++j) acc[wg][i][j] = (v4f)0.f;

    constexpr int NT = D_DIM / 32;   // 64
    stageB(0, 0);

    for (int ks = 0; ks < NT; ++ks) {
        __builtin_amdgcn_s_barrier();        // As & old B-buffer readers done
        stageA(ks * 32);
        if (ks + 1 < NT) {
            stageB((ks + 1) & 1, (ks + 1) * 32);
            asm volatile("s_waitcnt vmcnt(3)" ::: "memory");  // A(ks)+B(ks) landed
        } else {
            asm volatile("s_waitcnt vmcnt(0)" ::: "memory");
        }
        __builtin_amdgcn_s_barrier();        // staged data visible to all waves
        __builtin_amdgcn_sched_barrier(0);

        const ush* Bbase = qsmem + 8192 + (ks & 1) * 12288;

        v8s a_h[2], a_l[2];
#pragma unroll
        for (int mf = 0; mf < 2; ++mf) {
            const int r = wm * 32 + mf * 16 + cl;
            a_h[mf] = *(const v8s*)&As[r * 64 + ((rg ^ (r & 7)) * 8)];
            a_l[mf] = *(const v8s*)&As[r * 64 + (((rg + 4) ^ (r & 7)) * 8)];
        }
#pragma unroll
        for (int wg = 0; wg < 3; ++wg) {
            const ush* Bw = Bbase + wg * 4096;
            v8s b_h[2], b_l[2];
#pragma unroll
            for (int nf = 0; nf < 2; ++nf) {
                const int r = wn * 32 + nf * 16 + cl;
                b_h[nf] = *(const v8s*)&Bw[r * 64 + ((rg ^ (r & 7)) * 8)];
                b_l[nf] = *(const v8s*)&Bw[r * 64 + (((rg + 4) ^ (r & 7)) * 8)];
            }
#pragma unroll
            for (int mf = 0; mf < 2; ++mf)
#pragma unroll
                for (int nf = 0; nf < 2; ++nf) {
                    acc[wg][mf][nf] = MFMA16(a_h[mf], b_h[nf], acc[wg][mf][nf]);
                    acc[wg][mf][nf] = MFMA16(a_h[mf], b_l[nf], acc[wg][mf][nf]);
                    acc[wg][mf][nf] = MFMA16(a_l[mf], b_h[nf], acc[wg][mf][nf]);
                }
        }
        asm volatile("" ::: "memory");
    }

    // epilogue: Q scaled row-major, K row-major, V transposed
#pragma unroll
    for (int mf = 0; mf < 2; ++mf)
#pragma unroll
        for (int nf = 0; nf < 2; ++nf) {
            const int n  = n0 + wn * 32 + nf * 16 + cl;
            const int mb = m0 + wm * 32 + mf * 16 + rg * 4;
            const float bvq = bq[n], bvk = bk[n], bvv = bv[n];
#pragma unroll
            for (int j = 0; j < 4; ++j) {
                Qo[(size_t)(mb + j) * D_DIM + n] =
                    f2bf((acc[0][mf][nf][j] + bvq) * qscale);
                Ko[(size_t)(mb + j) * D_DIM + n] =
                    f2bf(acc[1][mf][nf][j] + bvk);
            }
            ushort4 pk;
            pk.x = f2bf(acc[2][mf][nf][0] + bvv);
            pk.y = f2bf(acc[2][mf][nf][1] + bvv);
            pk.z = f2bf(acc[2][mf][nf][2] + bvv);
            pk.w = f2bf(acc[2][mf][nf][3] + bvv);
            *(ushort4*)&Vto[(size_t)n * D_DIM + mb] = pk;
        }
}

// ---------------------------------------------------------------------------
// Causal flash attention, bf16 MFMA, in-block KV split, swapped operands.
// LDS 64 KB (Ps overlaid on Ks[0:8KB]) -> 2 blocks/CU. (proven — unchanged)
// ---------------------------------------------------------------------------
__global__ __launch_bounds__(512, 4) void attn_fused(
    const ush* __restrict__ Qg, const ush* __restrict__ Kg,
    const ush* __restrict__ Vtg,
    ush* __restrict__ Yh, ush* __restrict__ Yl)
{
    extern __shared__ char smem[];
    const int b   = blockIdx.x;
    const int h   = b & 15;
    const int qt  = 31 - (b >> 4);       // descending: long blocks first
    const int q0  = qt * 64;
    const int tid = threadIdx.x;
    const int l   = tid & 63;
    const int wid = tid >> 6;
    const int grp = wid >> 2;            // 0 or 1
    const int w   = wid & 3;             // wave: q rows [w*16, w*16+16)
    const int cl  = l & 15;
    const int rg  = l >> 4;
    const int clx = cl & 7;
    const int tg  = tid & 255;

    char* gbase = smem + grp * 32768;
    ush* Ks = (ush*)gbase;               // [64][128] swz, 16 KB
    ush* Vs = (ush*)(gbase + 16384);     // [128][64] swz, 16 KB
    ush* Ps = Ks;                        // overlaid on Ks[0:8KB]

    const int split = (qt + 2) >> 1;
    const int iters = split;
    const int t0    = grp ? split : 0;
    const int tcnt  = grp ? (qt + 1 - split) : split;

    const int qrow = q0 + w * 16 + cl;

    v8s qf[4];
#pragma unroll
    for (int kf = 0; kf < 4; ++kf)
        qf[kf] = *(const v8s*)&Qg[(size_t)qrow * D_DIM + h * DHEAD + kf * 32 + rg * 8];

    v4f acc[8];
#pragma unroll
    for (int nf = 0; nf < 8; ++nf) acc[nf] = (v4f)0.f;
    float mrow = -INFINITY;
    float lsum = 0.f;

    auto stage = [&](int tile) {
#pragma unroll
        for (int i = 0; i < 4; ++i) {
            const int id = i * 256 + tg;
            const int kr = id >> 4, kc = id & 15;
            gload_lds16(&Kg[(size_t)(tile * 64 + kr) * D_DIM + h * DHEAD +
                            ((kc ^ (kr & 7)) * 8)], &Ks[id * 8]);
        }
#pragma unroll
        for (int i = 0; i < 4; ++i) {
            const int id = i * 256 + tg;
            const int vr = id >> 3, vc = id & 7;
            gload_lds16(&Vtg[(size_t)(h * DHEAD + vr) * D_DIM + tile * 64 +
                             ((vc ^ (vr & 7)) * 8)], &Vs[id * 8]);
        }
    };

    for (int t = 0; t < iters; ++t) {
        __syncthreads();                 // prev tile's Ks/Vs/Ps reads done
        if (t < tcnt) stage(t0 + t);
        __syncthreads();                 // staged data valid
        const bool act = (t < tcnt);
        const int tile = t0 + t;
        uint2 pk[4];
        if (act) {
            v4f st[4];
#pragma unroll
            for (int n = 0; n < 4; ++n) st[n] = (v4f)0.f;
            __builtin_amdgcn_s_setprio(1);
#pragma unroll
            for (int kf = 0; kf < 4; ++kf) {
#pragma unroll
                for (int n = 0; n < 4; ++n) {
                    const v8s kfr = *(const v8s*)&Ks[(n * 16 + cl) * 128 +
                                     (((kf * 4 + rg) ^ clx) * 8)];
                    st[n] = MFMA16(kfr, qf[kf], st[n]);
                }
            }
            __builtin_amdgcn_s_setprio(0);

            float sv[4][4];
            const bool dm = (tile == qt);
#pragma unroll
            for (int n = 0; n < 4; ++n)
#pragma unroll
                for (int jj = 0; jj < 4; ++jj) {
                    float v = st[n][jj];
                    if (dm && (tile * 64 + n * 16 + rg * 4 + jj > qrow))
                        v = -INFINITY;
                    sv[n][jj] = v;
                }
            float mx = sv[0][0];
#pragma unroll
            for (int n = 0; n < 4; ++n)
#pragma unroll
                for (int jj = 0; jj < 4; ++jj) mx = fmaxf(mx, sv[n][jj]);
            mx = fmaxf(mx, __shfl_xor(mx, 16));
            mx = fmaxf(mx, __shfl_xor(mx, 32));
            const float mnew = fmaxf(mrow, mx);

            float rs = 0.f;
#pragma unroll
            for (int n = 0; n < 4; ++n) {
                float p0 = exp2f(sv[n][0] - mnew);
                float p1 = exp2f(sv[n][1] - mnew);
                float p2 = exp2f(sv[n][2] - mnew);
                float p3 = exp2f(sv[n][3] - mnew);
                rs += (p0 + p1) + (p2 + p3);
                pk[n].x = pack2(f2bf(p0), f2bf(p1));
                pk[n].y = pack2(f2bf(p2), f2bf(p3));
            }
            rs += __shfl_xor(rs, 16);
            rs += __shfl_xor(rs, 32);

            const float corr = exp2f(mrow - mnew);
            lsum = lsum * corr + rs;
            mrow = mnew;
#pragma unroll
            for (int nf = 0; nf < 8; ++nf) acc[nf] *= corr;
        }
        __syncthreads();                 // all Ks reads done -> Ps may overwrite
        if (act) {
#pragma unroll
            for (int n = 0; n < 4; ++n)
                *(uint2*)&Ps[(w * 16 + cl) * 64 +
                             (((2 * n + (rg >> 1)) ^ clx) * 8) + (rg & 1) * 4] = pk[n];
            const int pr = w * 16 + cl;
            v8s pa[2];
            pa[0] = *(const v8s*)&Ps[pr * 64 + ((rg ^ clx) * 8)];
            pa[1] = *(const v8s*)&Ps[pr * 64 + (((4 + rg) ^ clx) * 8)];
            __builtin_amdgcn_s_setprio(1);
#pragma unroll
            for (int nf = 0; nf < 8; ++nf) {
#pragma unroll
                for (int kk = 0; kk < 2; ++kk) {
                    const v8s vb = *(const v8s*)&Vs[(nf * 16 + cl) * 64 +
                                    (((kk * 4 + rg) ^ clx) * 8)];
                    acc[nf] = MFMA16(vb, pa[kk], acc[nf]);
                }
            }
            __builtin_amdgcn_s_setprio(0);
        }
    }

    // ---- in-LDS merge of the two KV-half partials (lane-local in q) ----
    float* mAcc = (float*)smem;              // [64][132] fp32, 33792 B
    float* mML  = (float*)(smem + 33792);    // [64][2]

    const int lr = w * 16 + cl;
    __syncthreads();                         // all compute done
    if (grp == 1) {
#pragma unroll
        for (int nf = 0; nf < 8; ++nf)
            *(v4f*)&mAcc[lr * 132 + nf * 16 + rg * 4] = acc[nf];
        if (rg == 0) {
            mML[lr * 2]     = mrow;
            mML[lr * 2 + 1] = lsum;
        }
    }
    __syncthreads();
    if (grp == 0) {
        const float m1 = mML[lr * 2];
        const float l1 = mML[lr * 2 + 1];
        const float ms = fmaxf(mrow, m1);
        const float e0 = exp2f(mrow - ms);
        const float e1 = exp2f(m1 - ms);
        const float inv = 1.0f / (lsum * e0 + l1 * e1);
        const float s0 = e0 * inv, s1 = e1 * inv;
#pragma unroll
        for (int nf = 0; nf < 8; ++nf) {
            const v4f a1 = *(const v4f*)&mAcc[lr * 132 + nf * 16 + rg * 4];
            float y[4];
#pragma unroll
            for (int j = 0; j < 4; ++j) y[j] = acc[nf][j] * s0 + a1[j] * s1;
            ushort4 ph, pl;
            ush hh;
            hh = f2bf(y[0]); ph.x = hh; pl.x = f2bf(y[0] - bf2f(hh));
            hh = f2bf(y[1]); ph.y = hh; pl.y = f2bf(y[1] - bf2f(hh));
            hh = f2bf(y[2]); ph.z = hh; pl.z = f2bf(y[2] - bf2f(hh));
            hh = f2bf(y[3]); ph.w = hh; pl.w = f2bf(y[3] - bf2f(hh));
            const size_t o = (size_t)(q0 + lr) * D_DIM + h * DHEAD + nf * 16 + rg * 4;
            *(ushort4*)&Yh[o] = ph;
            *(ushort4*)&Yl[o] = pl;
        }
    }
}

// ---------------------------------------------------------------------------
extern "C" void kernel_launch(void* const* d_in, const int* in_sizes, int n_in,
                              void* d_out, int out_size, void* d_ws, size_t ws_size,
                              hipStream_t stream)
{
    const float* x  = (const float*)d_in[0];
    const float* Wq = (const float*)d_in[1];
    const float* bq = (const float*)d_in[2];
    const float* Wk = (const float*)d_in[3];
    const float* bk = (const float*)d_in[4];
    const float* Wv = (const float*)d_in[5];
    const float* bv = (const float*)d_in[6];
    const float* Wo = (const float*)d_in[7];
    const float* bo = (const float*)d_in[8];
    float* out = (float*)d_out;

    const size_t mat = (size_t)T_DIM * D_DIM;
    // 1/sqrt(128) * log2(e): attention runs in exp2 domain
    const float qscale = 0.08838834764831845f * 1.4426950408889634f;

    const int attn_lds = 65536;
    const int gemm_lds = 65536;
    hipFuncSetAttribute((const void*)attn_fused,
                        hipFuncAttributeMaxDynamicSharedMemorySize, attn_lds);
    hipFuncSetAttribute((const void*)gemm_qkv,
                        hipFuncAttributeMaxDynamicSharedMemorySize, gemm_lds);
    hipFuncSetAttribute((const void*)gemm_x3<0>,
                        hipFuncAttributeMaxDynamicSharedMemorySize, gemm_lds);
    hipFuncSetAttribute((const void*)gemm_x3<1>,
                        hipFuncAttributeMaxDynamicSharedMemorySize, gemm_lds);
    hipFuncSetAttribute((const void*)gemm_x3<2>,
                        hipFuncAttributeMaxDynamicSharedMemorySize, gemm_lds);

    const size_t need_fused = 13 * mat * sizeof(ush);   // 109.1 MB

    if (ws_size >= need_fused) {
        // ---------------- fused path: 4 dispatches ----------------
        ush* xh  = (ush*)d_ws;
        ush* xl  = xh  + mat;
        ush* Qh  = xl  + mat;
        ush* Kh  = Qh  + mat;
        ush* Vth = Kh  + mat;
        ush* Wqh = Vth + mat;
        ush* Wql = Wqh + mat;
        ush* Wkh = Wql + mat;
        ush* Wkl = Wkh + mat;
        ush* Wvh = Wkl + mat;
        ush* Wvl = Wvh + mat;
        ush* Woh = Wvl + mat;
        ush* Wol = Woh + mat;
        ush* Yh  = xh;   // x dead after gemm_qkv
        ush* Yl  = xl;

        Split5Args sa;
        sa.s[0] = x;  sa.h[0] = xh;  sa.l[0] = xl;
        sa.s[1] = Wq; sa.h[1] = Wqh; sa.l[1] = Wql;
        sa.s[2] = Wk; sa.h[2] = Wkh; sa.l[2] = Wkl;
        sa.s[3] = Wv; sa.h[3] = Wvh; sa.l[3] = Wvl;
        sa.s[4] = Wo; sa.h[4] = Woh; sa.l[4] = Wol;
        split5<<<dim3(mat / 2048, 5), 256, 0, stream>>>(sa);

        gemm_qkv<<<512, 512, gemm_lds, stream>>>(
            xh, xl, Wqh, Wql, Wkh, Wkl, Wvh, Wvl, bq, bk, bv, qscale,
            Qh, Kh, Vth);

        attn_fused<<<512, 512, attn_lds, stream>>>(Qh, Kh, Vth, Yh, Yl);

        gemm_x3<2><<<512, 512, gemm_lds, stream>>>(Yh, Yl, Woh, Wol, bo, 1.0f,
                                                   nullptr, out);
    } else {
        // ---------------- fallback: proven round-5 sequence ----------------
        ush* xh  = (ush*)d_ws;
        ush* xl  = xh + mat;
        ush* Qh  = xl + mat;
        ush* Kh  = Qh + mat;
        ush* Vth = Kh + mat;
        ush* Wh  = Vth + mat;
        ush* Wl  = Wh + mat;
        ush* Yh  = xh;
        ush* Yl  = xl;

        split_x<<<mat / 2048, 256, 0, stream>>>(x, xh, xl);

        split_x<<<mat / 2048, 256, 0, stream>>>(Wq, Wh, Wl);
        gemm_x3<0><<<512, 512, gemm_lds, stream>>>(xh, xl, Wh, Wl, bq, qscale, Qh, nullptr);
        split_x<<<mat / 2048, 256, 0, stream>>>(Wk, Wh, Wl);
        gemm_x3<0><<<512, 512, gemm_lds, stream>>>(xh, xl, Wh, Wl, bk, 1.0f, Kh, nullptr);
        split_x<<<mat / 2048, 256, 0, stream>>>(Wv, Wh, Wl);
        gemm_x3<1><<<512, 512, gemm_lds, stream>>>(xh, xl, Wh, Wl, bv, 1.0f, Vth, nullptr);

        attn_fused<<<512, 512, attn_lds, stream>>>(Qh, Kh, Vth, Yh, Yl);

        split_x<<<mat / 2048, 256, 0, stream>>>(Wo, Wh, Wl);
        gemm_x3<2><<<512, 512, gemm_lds, stream>>>(Yh, Yl, Wh, Wl, bo, 1.0f, nullptr, out);
    }
}

// Round 11
// 156.746 us; speedup vs baseline: 1.6756x; 1.6756x over previous
//
#include <hip/hip_runtime.h>
#include <hip/hip_fp16.h>
#include <math.h>

#define T_DIM 2048
#define D_DIM 2048
#define NHEAD 16
#define DHEAD 128

typedef _Float16 h8 __attribute__((ext_vector_type(8)));   // 8 fp16 (4 VGPRs)
typedef float v4f __attribute__((ext_vector_type(4)));
typedef unsigned short ush;

#define MFMAH(a, b, c) __builtin_amdgcn_mfma_f32_16x16x32_f16((a), (b), (c), 0, 0, 0)

__device__ __forceinline__ ush f2h(float f) {
    return __half_as_ushort(__float2half(f));   // RTN
}
__device__ __forceinline__ unsigned pack2(ush a, ush b) {
    return (unsigned)a | ((unsigned)b << 16);
}

__device__ __forceinline__ void gload_lds16(const ush* g, ush* l) {
    __builtin_amdgcn_global_load_lds(
        (const __attribute__((address_space(1))) void*)g,
        (__attribute__((address_space(3))) void*)l, 16, 0, 0);
}

// 2-D region XCD swizzle for a 16(m) x 32(n) grid of 512 blocks (proven r9:
// FETCH 232->82MB). Each XCD owns an 8m x 8n region.
__device__ __forceinline__ void region_swizzle(int bid, int& m0, int& n0) {
    const int xcd = bid & 7;
    const int lg  = bid >> 3;
    const int mp  = ((xcd >> 2) << 3) + (lg >> 3);
    const int np  = ((xcd & 3) << 3) + (lg & 7);
    m0 = mp * 128;
    n0 = np * 64;
}

// ---------------------------------------------------------------------------
// Fused 5-matrix fp32 -> fp16 cast (x, Wq, Wk, Wv, Wo).
// ---------------------------------------------------------------------------
struct Cvt5Args { const float* s[5]; ush* d[5]; };

__global__ __launch_bounds__(256) void cvt5(Cvt5Args a)
{
    const int m = blockIdx.y;
    const float* X = a.s[m];
    ush* Dst = a.d[m];
    const int i = (blockIdx.x * 256 + threadIdx.x) * 8;
    const float4 p = *(const float4*)&X[i];
    const float4 q = *(const float4*)&X[i + 4];
    uint4 o;
    o.x = pack2(f2h(p.x), f2h(p.y));
    o.y = pack2(f2h(p.z), f2h(p.w));
    o.z = pack2(f2h(q.x), f2h(q.y));
    o.w = pack2(f2h(q.z), f2h(q.w));
    *(uint4*)&Dst[i] = o;
}

// ---------------------------------------------------------------------------
// FUSED QKV GEMM, plain fp16 (1 MFMA per tile — was bf16x3's 3).
// Block 128x64, BK=64, 256 threads = 4 waves (2m x 2n), wave-tile 64x32:
// reads/wave/step = 8(A)+12(B) b128 for 48 MFMA (2.4 MFMA/read, was 1.5).
// LDS: A[128][64] 16KB + 3x B[64][64] 8KB = 40KB static. 2-phase barriers
// (r10's counted-vmcnt was null). Region swizzle. Rows = 128B, XOR(row&7)
// over 8 chunks -> 0 bank conflicts (r7-proven geometry).
// ---------------------------------------------------------------------------
__global__ __launch_bounds__(256, 2) void gemm_qkv_f16(
    const ush* __restrict__ xf,
    const ush* __restrict__ Wqf, const ush* __restrict__ Wkf,
    const ush* __restrict__ Wvf,
    const float* __restrict__ bq, const float* __restrict__ bk,
    const float* __restrict__ bv, float qscale,
    ush* __restrict__ Qo, ush* __restrict__ Ko, ush* __restrict__ Vto)
{
    __shared__ ush As[128 * 64];
    __shared__ ush Bs[3][64 * 64];

    const int tid = threadIdx.x;
    const int l   = tid & 63;
    const int wid = tid >> 6;      // 0..3
    const int wm  = wid >> 1;      // 0..1 (m half)
    const int wn  = wid & 1;       // 0..1 (n half)
    const int cl  = l & 15;
    const int rg  = l >> 4;

    int m0, n0;
    region_swizzle(blockIdx.x, m0, n0);

    const ush* Wf[3] = {Wqf, Wkf, Wvf};

    v4f acc[3][4][2];
#pragma unroll
    for (int wg = 0; wg < 3; ++wg)
#pragma unroll
        for (int mf = 0; mf < 4; ++mf)
#pragma unroll
            for (int nf = 0; nf < 2; ++nf) acc[wg][mf][nf] = (v4f)0.f;

    for (int ks = 0; ks < D_DIM / 64; ++ks) {
        const int k0 = ks * 64;
        __syncthreads();
        // A: 128 rows x 8 chunks = 1024 slots, 4 per thread
#pragma unroll
        for (int i = 0; i < 4; ++i) {
            const int p   = i * 256 + tid;
            const int row = p >> 3;
            const int lc  = (p & 7) ^ (row & 7);
            gload_lds16(&xf[(size_t)(m0 + row) * D_DIM + k0 + lc * 8], &As[p * 8]);
        }
        // B: 64 rows x 8 chunks = 512 slots per weight, 2 per thread each
#pragma unroll
        for (int i = 0; i < 2; ++i) {
            const int p   = i * 256 + tid;
            const int row = p >> 3;
            const int lc  = (p & 7) ^ (row & 7);
            const size_t off = (size_t)(n0 + row) * D_DIM + k0 + lc * 8;
#pragma unroll
            for (int wg = 0; wg < 3; ++wg)
                gload_lds16(&Wf[wg][off], &Bs[wg][p * 8]);
        }
        __syncthreads();

#pragma unroll
        for (int kf = 0; kf < 2; ++kf) {
            const int c = kf * 4 + rg;
            h8 a[4];
#pragma unroll
            for (int mf = 0; mf < 4; ++mf) {
                const int r = wm * 64 + mf * 16 + cl;
                a[mf] = *(const h8*)&As[r * 64 + ((c ^ (r & 7)) * 8)];
            }
#pragma unroll
            for (int wg = 0; wg < 3; ++wg) {
                h8 b[2];
#pragma unroll
                for (int nf = 0; nf < 2; ++nf) {
                    const int r = wn * 32 + nf * 16 + cl;
                    b[nf] = *(const h8*)&Bs[wg][r * 64 + ((c ^ (r & 7)) * 8)];
                }
#pragma unroll
                for (int mf = 0; mf < 4; ++mf)
#pragma unroll
                    for (int nf = 0; nf < 2; ++nf)
                        acc[wg][mf][nf] = MFMAH(a[mf], b[nf], acc[wg][mf][nf]);
            }
        }
    }

    // epilogue: Q scaled row-major, K row-major, V transposed — all fp16
#pragma unroll
    for (int mf = 0; mf < 4; ++mf)
#pragma unroll
        for (int nf = 0; nf < 2; ++nf) {
            const int n  = n0 + wn * 32 + nf * 16 + cl;
            const int mb = m0 + wm * 64 + mf * 16 + rg * 4;
            const float bvq = bq[n], bvk = bk[n], bvv = bv[n];
#pragma unroll
            for (int j = 0; j < 4; ++j) {
                Qo[(size_t)(mb + j) * D_DIM + n] =
                    f2h((acc[0][mf][nf][j] + bvq) * qscale);
                Ko[(size_t)(mb + j) * D_DIM + n] =
                    f2h(acc[1][mf][nf][j] + bvk);
            }
            ushort4 pk;
            pk.x = f2h(acc[2][mf][nf][0] + bvv);
            pk.y = f2h(acc[2][mf][nf][1] + bvv);
            pk.z = f2h(acc[2][mf][nf][2] + bvv);
            pk.w = f2h(acc[2][mf][nf][3] + bvv);
            *(ushort4*)&Vto[(size_t)n * D_DIM + mb] = pk;   // Vt[n][m..m+3]
        }
}

// ---------------------------------------------------------------------------
// O-projection GEMM, plain fp16: out = Y @ Wo^T + bo (fp32 out).
// Same 256-thread / 64x32 wave-tile / BK=64 structure.
// ---------------------------------------------------------------------------
__global__ __launch_bounds__(256, 2) void gemm_o_f16(
    const ush* __restrict__ Yf, const ush* __restrict__ Wof,
    const float* __restrict__ bo, float* __restrict__ out)
{
    __shared__ ush As[128 * 64];
    __shared__ ush Bs[64 * 64];

    const int tid = threadIdx.x;
    const int l   = tid & 63;
    const int wid = tid >> 6;
    const int wm  = wid >> 1;
    const int wn  = wid & 1;
    const int cl  = l & 15;
    const int rg  = l >> 4;

    int m0, n0;
    region_swizzle(blockIdx.x, m0, n0);

    v4f acc[4][2];
#pragma unroll
    for (int mf = 0; mf < 4; ++mf)
#pragma unroll
        for (int nf = 0; nf < 2; ++nf) acc[mf][nf] = (v4f)0.f;

    for (int ks = 0; ks < D_DIM / 64; ++ks) {
        const int k0 = ks * 64;
        __syncthreads();
#pragma unroll
        for (int i = 0; i < 4; ++i) {
            const int p   = i * 256 + tid;
            const int row = p >> 3;
            const int lc  = (p & 7) ^ (row & 7);
            gload_lds16(&Yf[(size_t)(m0 + row) * D_DIM + k0 + lc * 8], &As[p * 8]);
        }
#pragma unroll
        for (int i = 0; i < 2; ++i) {
            const int p   = i * 256 + tid;
            const int row = p >> 3;
            const int lc  = (p & 7) ^ (row & 7);
            gload_lds16(&Wof[(size_t)(n0 + row) * D_DIM + k0 + lc * 8], &Bs[p * 8]);
        }
        __syncthreads();

#pragma unroll
        for (int kf = 0; kf < 2; ++kf) {
            const int c = kf * 4 + rg;
            h8 a[4], b[2];
#pragma unroll
            for (int mf = 0; mf < 4; ++mf) {
                const int r = wm * 64 + mf * 16 + cl;
                a[mf] = *(const h8*)&As[r * 64 + ((c ^ (r & 7)) * 8)];
            }
#pragma unroll
            for (int nf = 0; nf < 2; ++nf) {
                const int r = wn * 32 + nf * 16 + cl;
                b[nf] = *(const h8*)&Bs[r * 64 + ((c ^ (r & 7)) * 8)];
            }
#pragma unroll
            for (int mf = 0; mf < 4; ++mf)
#pragma unroll
                for (int nf = 0; nf < 2; ++nf)
                    acc[mf][nf] = MFMAH(a[mf], b[nf], acc[mf][nf]);
        }
    }

#pragma unroll
    for (int mf = 0; mf < 4; ++mf)
#pragma unroll
        for (int nf = 0; nf < 2; ++nf) {
            const int n  = n0 + wn * 32 + nf * 16 + cl;
            const int mb = m0 + wm * 64 + mf * 16 + rg * 4;
            const float bv = bo[n];
#pragma unroll
            for (int j = 0; j < 4; ++j)
                out[(size_t)(mb + j) * D_DIM + n] = acc[mf][nf][j] + bv;
        }
}

// ---------------------------------------------------------------------------
// Causal flash attention, fp16 MFMA, in-block KV split, swapped operands.
// Structure identical to the proven r5-r10 kernel; types bf16 -> fp16
// (strictly more accurate), Y now a SINGLE fp16 array (no hi/lo split).
// LDS 64 KB (Ps overlaid on Ks[0:8KB]) -> 2 blocks/CU.
// ---------------------------------------------------------------------------
__global__ __launch_bounds__(512, 4) void attn_fused(
    const ush* __restrict__ Qg, const ush* __restrict__ Kg,
    const ush* __restrict__ Vtg, ush* __restrict__ Yf)
{
    extern __shared__ char smem[];
    const int b   = blockIdx.x;
    const int h   = b & 15;
    const int qt  = 31 - (b >> 4);       // descending: long blocks first
    const int q0  = qt * 64;
    const int tid = threadIdx.x;
    const int l   = tid & 63;
    const int wid = tid >> 6;
    const int grp = wid >> 2;            // 0 or 1
    const int w   = wid & 3;             // wave: q rows [w*16, w*16+16)
    const int cl  = l & 15;
    const int rg  = l >> 4;
    const int clx = cl & 7;
    const int tg  = tid & 255;

    char* gbase = smem + grp * 32768;
    ush* Ks = (ush*)gbase;               // [64][128] swz, 16 KB
    ush* Vs = (ush*)(gbase + 16384);     // [128][64] swz, 16 KB
    ush* Ps = Ks;                        // overlaid on Ks[0:8KB]

    const int split = (qt + 2) >> 1;
    const int iters = split;
    const int t0    = grp ? split : 0;
    const int tcnt  = grp ? (qt + 1 - split) : split;

    const int qrow = q0 + w * 16 + cl;

    h8 qf[4];
#pragma unroll
    for (int kf = 0; kf < 4; ++kf)
        qf[kf] = *(const h8*)&Qg[(size_t)qrow * D_DIM + h * DHEAD + kf * 32 + rg * 8];

    v4f acc[8];
#pragma unroll
    for (int nf = 0; nf < 8; ++nf) acc[nf] = (v4f)0.f;
    float mrow = -INFINITY;
    float lsum = 0.f;

    auto stage = [&](int tile) {
#pragma unroll
        for (int i = 0; i < 4; ++i) {
            const int id = i * 256 + tg;
            const int kr = id >> 4, kc = id & 15;
            gload_lds16(&Kg[(size_t)(tile * 64 + kr) * D_DIM + h * DHEAD +
                            ((kc ^ (kr & 7)) * 8)], &Ks[id * 8]);
        }
#pragma unroll
        for (int i = 0; i < 4; ++i) {
            const int id = i * 256 + tg;
            const int vr = id >> 3, vc = id & 7;
            gload_lds16(&Vtg[(size_t)(h * DHEAD + vr) * D_DIM + tile * 64 +
                             ((vc ^ (vr & 7)) * 8)], &Vs[id * 8]);
        }
    };

    for (int t = 0; t < iters; ++t) {
        __syncthreads();                 // prev tile's Ks/Vs/Ps reads done
        if (t < tcnt) stage(t0 + t);
        __syncthreads();                 // staged data valid
        const bool act = (t < tcnt);
        const int tile = t0 + t;
        uint2 pk[4];
        if (act) {
            v4f st[4];
#pragma unroll
            for (int n = 0; n < 4; ++n) st[n] = (v4f)0.f;
            __builtin_amdgcn_s_setprio(1);
#pragma unroll
            for (int kf = 0; kf < 4; ++kf) {
#pragma unroll
                for (int n = 0; n < 4; ++n) {
                    const h8 kfr = *(const h8*)&Ks[(n * 16 + cl) * 128 +
                                    (((kf * 4 + rg) ^ clx) * 8)];
                    st[n] = MFMAH(kfr, qf[kf], st[n]);
                }
            }
            __builtin_amdgcn_s_setprio(0);

            float sv[4][4];
            const bool dm = (tile == qt);
#pragma unroll
            for (int n = 0; n < 4; ++n)
#pragma unroll
                for (int jj = 0; jj < 4; ++jj) {
                    float v = st[n][jj];
                    if (dm && (tile * 64 + n * 16 + rg * 4 + jj > qrow))
                        v = -INFINITY;
                    sv[n][jj] = v;
                }
            float mx = sv[0][0];
#pragma unroll
            for (int n = 0; n < 4; ++n)
#pragma unroll
                for (int jj = 0; jj < 4; ++jj) mx = fmaxf(mx, sv[n][jj]);
            mx = fmaxf(mx, __shfl_xor(mx, 16));
            mx = fmaxf(mx, __shfl_xor(mx, 32));
            const float mnew = fmaxf(mrow, mx);

            float rs = 0.f;
#pragma unroll
            for (int n = 0; n < 4; ++n) {
                float p0 = exp2f(sv[n][0] - mnew);
                float p1 = exp2f(sv[n][1] - mnew);
                float p2 = exp2f(sv[n][2] - mnew);
                float p3 = exp2f(sv[n][3] - mnew);
                rs += (p0 + p1) + (p2 + p3);
                pk[n].x = pack2(f2h(p0), f2h(p1));
                pk[n].y = pack2(f2h(p2), f2h(p3));
            }
            rs += __shfl_xor(rs, 16);
            rs += __shfl_xor(rs, 32);

            const float corr = exp2f(mrow - mnew);
            lsum = lsum * corr + rs;
            mrow = mnew;
#pragma unroll
            for (int nf = 0; nf < 8; ++nf) acc[nf] *= corr;
        }
        __syncthreads();                 // all Ks reads done -> Ps may overwrite
        if (act) {
#pragma unroll
            for (int n = 0; n < 4; ++n)
                *(uint2*)&Ps[(w * 16 + cl) * 64 +
                             (((2 * n + (rg >> 1)) ^ clx) * 8) + (rg & 1) * 4] = pk[n];
            const int pr = w * 16 + cl;
            h8 pa[2];
            pa[0] = *(const h8*)&Ps[pr * 64 + ((rg ^ clx) * 8)];
            pa[1] = *(const h8*)&Ps[pr * 64 + (((4 + rg) ^ clx) * 8)];
            __builtin_amdgcn_s_setprio(1);
#pragma unroll
            for (int nf = 0; nf < 8; ++nf) {
#pragma unroll
                for (int kk = 0; kk < 2; ++kk) {
                    const h8 vb = *(const h8*)&Vs[(nf * 16 + cl) * 64 +
                                   (((kk * 4 + rg) ^ clx) * 8)];
                    acc[nf] = MFMAH(vb, pa[kk], acc[nf]);
                }
            }
            __builtin_amdgcn_s_setprio(0);
        }
    }

    // ---- in-LDS merge of the two KV-half partials (lane-local in q) ----
    float* mAcc = (float*)smem;              // [64][132] fp32, 33792 B
    float* mML  = (float*)(smem + 33792);    // [64][2]

    const int lr = w * 16 + cl;
    __syncthreads();                         // all compute done
    if (grp == 1) {
#pragma unroll
        for (int nf = 0; nf < 8; ++nf)
            *(v4f*)&mAcc[lr * 132 + nf * 16 + rg * 4] = acc[nf];
        if (rg == 0) {
            mML[lr * 2]     = mrow;
            mML[lr * 2 + 1] = lsum;
        }
    }
    __syncthreads();
    if (grp == 0) {
        const float m1 = mML[lr * 2];
        const float l1 = mML[lr * 2 + 1];
        const float ms = fmaxf(mrow, m1);
        const float e0 = exp2f(mrow - ms);
        const float e1 = exp2f(m1 - ms);
        const float inv = 1.0f / (lsum * e0 + l1 * e1);
        const float s0 = e0 * inv, s1 = e1 * inv;
#pragma unroll
        for (int nf = 0; nf < 8; ++nf) {
            const v4f a1 = *(const v4f*)&mAcc[lr * 132 + nf * 16 + rg * 4];
            ushort4 ph;
            ph.x = f2h(acc[nf][0] * s0 + a1[0] * s1);
            ph.y = f2h(acc[nf][1] * s0 + a1[1] * s1);
            ph.z = f2h(acc[nf][2] * s0 + a1[2] * s1);
            ph.w = f2h(acc[nf][3] * s0 + a1[3] * s1);
            const size_t o = (size_t)(q0 + lr) * D_DIM + h * DHEAD + nf * 16 + rg * 4;
            *(ushort4*)&Yf[o] = ph;
        }
    }
}

// ---------------------------------------------------------------------------
extern "C" void kernel_launch(void* const* d_in, const int* in_sizes, int n_in,
                              void* d_out, int out_size, void* d_ws, size_t ws_size,
                              hipStream_t stream)
{
    const float* x  = (const float*)d_in[0];
    const float* Wq = (const float*)d_in[1];
    const float* bq = (const float*)d_in[2];
    const float* Wk = (const float*)d_in[3];
    const float* bk = (const float*)d_in[4];
    const float* Wv = (const float*)d_in[5];
    const float* bv = (const float*)d_in[6];
    const float* Wo = (const float*)d_in[7];
    const float* bo = (const float*)d_in[8];
    float* out = (float*)d_out;

    const size_t mat = (size_t)T_DIM * D_DIM;
    // 1/sqrt(128) * log2(e): attention runs in exp2 domain
    const float qscale = 0.08838834764831845f * 1.4426950408889634f;

    const int attn_lds = 65536;
    hipFuncSetAttribute((const void*)attn_fused,
                        hipFuncAttributeMaxDynamicSharedMemorySize, attn_lds);

    // workspace: 8 fp16 matrices = 67.1 MB (harness provides >= 109 MB)
    ush* xf   = (ush*)d_ws;        // becomes Yf after QKV (x dead then)
    ush* Qf   = xf  + mat;
    ush* Kf   = Qf  + mat;
    ush* Vtf  = Kf  + mat;
    ush* Wqf  = Vtf + mat;
    ush* Wkf  = Wqf + mat;
    ush* Wvf  = Wkf + mat;
    ush* Wof  = Wvf + mat;
    ush* Yf   = xf;

    Cvt5Args ca;
    ca.s[0] = x;  ca.d[0] = xf;
    ca.s[1] = Wq; ca.d[1] = Wqf;
    ca.s[2] = Wk; ca.d[2] = Wkf;
    ca.s[3] = Wv; ca.d[3] = Wvf;
    ca.s[4] = Wo; ca.d[4] = Wof;
    cvt5<<<dim3(mat / 2048, 5), 256, 0, stream>>>(ca);

    gemm_qkv_f16<<<512, 256, 0, stream>>>(
        xf, Wqf, Wkf, Wvf, bq, bk, bv, qscale, Qf, Kf, Vtf);

    attn_fused<<<512, 512, attn_lds, stream>>>(Qf, Kf, Vtf, Yf);

    gemm_o_f16<<<512, 256, 0, stream>>>(Yf, Wof, bo, out);
}